// Round 13
// baseline (391.456 us; speedup 1.0000x reference)
//
#include <hip/hip_runtime.h>

// Problem constants
constexpr int Bb = 2;
constexpr int Ll = 2048;
constexpr int Dd = 2048;
constexpr int Hh = 16;
constexpr int Hd = 128;
constexpr int M  = Bb * Ll;   // 4096

typedef __attribute__((ext_vector_type(8)))  short s16x8;   // 8 bf16 (4 VGPRs)
typedef __attribute__((ext_vector_type(4)))  float f32x4;   // 16x16 C/D
typedef __attribute__((ext_vector_type(16))) float f32x16;  // 32x32 C/D

__device__ __forceinline__ unsigned short f2bf(float f) {
    union { float f; unsigned u; } v; v.f = f;
    unsigned r = v.u + 0x7fffu + ((v.u >> 16) & 1u);   // RNE
    return (unsigned short)(r >> 16);
}
__device__ __forceinline__ float bf2f(unsigned short b) {
    union { unsigned u; float f; } v; v.u = ((unsigned)b) << 16;
    return v.f;
}
__device__ __forceinline__ float fast_exp2(float x) {
#if __has_builtin(__builtin_amdgcn_exp2f)
    return __builtin_amdgcn_exp2f(x);
#else
    return exp2f(x);
#endif
}

// async global->LDS, 16 B per lane; lds dest = wave-uniform base + lane*16
__device__ __forceinline__ void gld16(const void* g, void* l) {
#if __has_builtin(__builtin_amdgcn_global_load_lds)
    __builtin_amdgcn_global_load_lds(
        (const __attribute__((address_space(1))) unsigned int*)g,
        (__attribute__((address_space(3))) unsigned int*)l, 16, 0, 0);
#else
    int lane = threadIdx.x & 63;
    ((int4*)l)[lane] = ((const int4*)g)[0];
#endif
}

// ---------------------------------------------------------------------------
// fp32 -> bf16 conversion, all 5 tensors in ONE launch.
// Segments (exact 1024-elem blocks): X 8192 | wq 4096 | wk 4096 | wv 4096 |
// wo 4096 = 24576 blocks total.
// ---------------------------------------------------------------------------
__global__ __launch_bounds__(256)
void f2bf_all(const float* __restrict__ x,  const float* __restrict__ wq,
              const float* __restrict__ wk, const float* __restrict__ wv,
              const float* __restrict__ wo,
              unsigned short* __restrict__ Xb,  unsigned short* __restrict__ Wqb,
              unsigned short* __restrict__ Wkb, unsigned short* __restrict__ Wvb,
              unsigned short* __restrict__ Wob)
{
    int bid = blockIdx.x;
    const float* in; unsigned short* out; int off;
    if      (bid <  8192) { in = x;  out = Xb;  off = bid; }
    else if (bid < 12288) { in = wq; out = Wqb; off = bid - 8192; }
    else if (bid < 16384) { in = wk; out = Wkb; off = bid - 12288; }
    else if (bid < 20480) { in = wv; out = Wvb; off = bid - 16384; }
    else                  { in = wo; out = Wob; off = bid - 20480; }
    int i = (off * 256 + threadIdx.x) * 4;
    float4 v = *(const float4*)(in + i);
    ushort4 o;
    o.x = f2bf(v.x); o.y = f2bf(v.y); o.z = f2bf(v.z); o.w = f2bf(v.w);
    *(ushort4*)(out + i) = o;
}

// ---------------------------------------------------------------------------
// Fused QKV GEMM + RoPE epilogue: C = A * Wall^T.  A [4096][2048] bf16,
// Wall [6144][2048] (wq;wk;wv stacked).
// BM=128 x BN=128 (R12-proven out-proj structure, ~982 TF), BK=64,
// 256 threads = 4 waves (2M x 2N), per-wave 64x64.  LDS main loop: 2 slots x
// 32 KiB; epilogue aliases the same buffer as fp32 [128][132] (67.6 KB total
// alloc -> still 2 blocks/CU).  Grid 48x32 = 1536 blocks = 3 rounds of 512.
// BN=128 => each block covers exactly ONE head of q, k, or v
// (nsel = bx>>4, h = bx&15), so the RoPE pair d <-> d^64 lives in-block:
// q/k epilogue dumps fp32 acc to LDS, barriers, then each thread ropes one
// 64-wide half-row (cos/sin from the L2-hot 1 MB tables), folds the
// QS = log2(e)/sqrt(128) scale into q, rounds once to bf16, stores.
// This DELETES the separate rope kernel (+its ~15 us launch gap) and applies
// rope before bf16 rounding (closer to the fp32 reference).
// v epilogue: transposed [b][h][d][l] store (unchanged).
// ---------------------------------------------------------------------------
__global__ __launch_bounds__(256, 2)
void mfma_gemm_qkv(const unsigned short* __restrict__ A,
                   const unsigned short* __restrict__ Wall,
                   const float* __restrict__ cosb,
                   const float* __restrict__ sinb,
                   unsigned short* __restrict__ Oq,
                   unsigned short* __restrict__ Ok,
                   unsigned short* __restrict__ Ov)
{
    constexpr int K  = 2048;
    constexpr int NT = K / 64;              // 32 K-tiles
    constexpr int BM = 128, BN = 128;
    constexpr int SLOT_US = (BM + BN) * 64; // 16384 ushorts = 32 KiB

    // 67584 B: main loop uses first 65536 B as 2 staging slots; epilogue
    // aliases the whole thing as fp32 [128][132].
    __shared__ float ldsf[128 * 132];
    unsigned short* lds = (unsigned short*)ldsf;

    const int t    = threadIdx.x;
    const int w    = t >> 6, lane = t & 63;
    const int wm   = w >> 1, wn = w & 1;          // 2M x 2N
    const int bx   = blockIdx.x;                  // 0..47
    const int nsel = bx >> 4;                     // 0=q, 1=k, 2=v
    const int h    = bx & 15;                     // head
    const int m0   = blockIdx.y * BM, n0 = bx * BN;
    const int r16  = lane & 15, q4 = lane >> 4;
    const int lxor = (r16 & 7) << 4;              // read-side swizzle XOR

    // staging lane constants: 8 lanes per 128B row; swizzled source column
    const int srow8 = lane >> 3;
    const int sgcol = (((lane & 7) ^ srow8) << 4);
    const char* Agb = (const char*)A;
    const char* Wgb = (const char*)Wall;

    f32x4 acc[4][4];
#pragma unroll
    for (int i = 0; i < 4; ++i)
#pragma unroll
        for (int j = 0; j < 4; ++j)
            acc[i][j] = (f32x4){0.f, 0.f, 0.f, 0.f};

// stage full K-tile: A 16 gld (ia=w*4+p), B 16 gld (ib=w*4+p); 8 per wave
#define STAGE_ALL(tt, sl) do {                                               \
    _Pragma("unroll") for (int p = 0; p < 4; ++p) {                          \
        int ia_ = w * 4 + p;                                                 \
        gld16(Agb + (size_t)(m0 + ia_ * 8 + srow8) * (K * 2) + (tt) * 128 + sgcol, \
              &lds[(sl) * SLOT_US + ia_ * 512]);                             \
    }                                                                        \
    _Pragma("unroll") for (int p = 0; p < 4; ++p) {                          \
        int ib_ = w * 4 + p;                                                 \
        gld16(Wgb + (size_t)(n0 + ib_ * 8 + srow8) * (K * 2) + (tt) * 128 + sgcol, \
              &lds[(sl) * SLOT_US + BM * 64 + ib_ * 512]);                   \
    }                                                                        \
} while (0)

#define MFMA16() do {                                                        \
    __builtin_amdgcn_s_setprio(1);                                           \
    _Pragma("unroll") for (int mi = 0; mi < 4; ++mi)                         \
    _Pragma("unroll") for (int ni = 0; ni < 4; ++ni)                         \
        acc[mi][ni] = __builtin_amdgcn_mfma_f32_16x16x32_bf16(                \
            a[mi], b[ni], acc[mi][ni], 0, 0, 0);                             \
    __builtin_amdgcn_s_setprio(0);                                           \
} while (0)

    STAGE_ALL(0, 0);
    asm volatile("s_waitcnt vmcnt(0)" ::: "memory");
    __builtin_amdgcn_s_barrier();
    asm volatile("" ::: "memory");

    for (int tt = 0; tt < NT; ++tt) {
        const int slot = tt & 1;
        const char* Ab = (const char*)&lds[slot * SLOT_US];
        const char* Bp = (const char*)&lds[slot * SLOT_US + BM * 64];
        const int c0 = (q4 * 16) ^ lxor;         // ksub0 byte col (swizzled)
        const int c1 = (64 + q4 * 16) ^ lxor;    // ksub1

        s16x8 a[4], b[4];

#pragma unroll
        for (int mi = 0; mi < 4; ++mi)
            a[mi] = *(const s16x8*)(Ab + (wm * 64 + mi * 16 + r16) * 128 + c0);
#pragma unroll
        for (int ni = 0; ni < 4; ++ni)
            b[ni] = *(const s16x8*)(Bp + (wn * 64 + ni * 16 + r16) * 128 + c0);
        if (tt + 1 < NT) STAGE_ALL(tt + 1, slot ^ 1);
        MFMA16();

#pragma unroll
        for (int mi = 0; mi < 4; ++mi)
            a[mi] = *(const s16x8*)(Ab + (wm * 64 + mi * 16 + r16) * 128 + c1);
#pragma unroll
        for (int ni = 0; ni < 4; ++ni)
            b[ni] = *(const s16x8*)(Bp + (wn * 64 + ni * 16 + r16) * 128 + c1);
        MFMA16();

        asm volatile("s_waitcnt vmcnt(0)" ::: "memory");  // t+1 staged
        __builtin_amdgcn_s_barrier();
        asm volatile("" ::: "memory");
    }
#undef STAGE_ALL
#undef MFMA16

    if (nsel == 2) {
        // v: transposed store [b][h][d][l]; lane holds 4 consecutive l
#pragma unroll
        for (int mi = 0; mi < 4; ++mi) {
            int mb = m0 + wm * 64 + mi * 16 + q4 * 4;
            int b = mb >> 11, l = mb & 2047;
#pragma unroll
            for (int ni = 0; ni < 4; ++ni) {
                int d = wn * 64 + ni * 16 + r16;
                ushort4 pk;
                pk.x = f2bf(acc[mi][ni][0]);
                pk.y = f2bf(acc[mi][ni][1]);
                pk.z = f2bf(acc[mi][ni][2]);
                pk.w = f2bf(acc[mi][ni][3]);
                *(ushort4*)&Ov[(((size_t)b * Hh + h) * Hd + d) * Ll + l] = pk;
            }
        }
    } else {
        // q/k: fused RoPE.  acc -> LDS fp32 [128][132] -> rope -> bf16 store.
        // (all staging reads retired at the loop's final barrier; LDS free)
#pragma unroll
        for (int mi = 0; mi < 4; ++mi)
#pragma unroll
            for (int ni = 0; ni < 4; ++ni) {
                int col = wn * 64 + ni * 16 + r16;
#pragma unroll
                for (int r = 0; r < 4; ++r) {
                    int row = wm * 64 + mi * 16 + q4 * 4 + r;
                    ldsf[row * 132 + col] = acc[mi][ni][r];
                }
            }
        __syncthreads();

        const float sc  = (nsel == 0) ? 0.1275175f : 1.0f;  // log2(e)/sqrt(128)
        unsigned short* O = (nsel == 0) ? Oq : Ok;
        const int row = t >> 1;                 // 0..127
        const int d0  = (t & 1) * 64;           // half-row
        const float sgn = (t & 1) ? 1.f : -1.f; // rotate_half sign
        const int m = m0 + row, b = m >> 11, l = m & 2047;
        const float* Lr = ldsf + row * 132;
        const float* cp = cosb + (size_t)l * Hd + d0;
        const float* sp = sinb + (size_t)l * Hd + d0;
        unsigned short* Orow = O + (((size_t)b * Hh + h) * Ll + l) * Hd + d0;
#pragma unroll
        for (int j = 0; j < 64; j += 4) {
            float4 c4 = *(const float4*)(cp + j);
            float4 s4 = *(const float4*)(sp + j);
            float x0, xp;
            ushort4 pk;
            x0 = Lr[d0 + j + 0]; xp = Lr[(d0 ^ 64) + j + 0];
            pk.x = f2bf(fmaf(x0, c4.x, sgn * xp * s4.x) * sc);
            x0 = Lr[d0 + j + 1]; xp = Lr[(d0 ^ 64) + j + 1];
            pk.y = f2bf(fmaf(x0, c4.y, sgn * xp * s4.y) * sc);
            x0 = Lr[d0 + j + 2]; xp = Lr[(d0 ^ 64) + j + 2];
            pk.z = f2bf(fmaf(x0, c4.z, sgn * xp * s4.z) * sc);
            x0 = Lr[d0 + j + 3]; xp = Lr[(d0 ^ 64) + j + 3];
            pk.w = f2bf(fmaf(x0, c4.w, sgn * xp * s4.w) * sc);
            *(ushort4*)(Orow + j) = pk;
        }
    }
}

// ---------------------------------------------------------------------------
// Out-projection GEMM (R12-proven): C = A * W^T, fp32.
// BM=128 x BN=128, BK=64, 256 threads = 4 waves (2M x 2N), per-wave 64x64.
// LDS: 2 slots x 32 KiB = 64 KiB -> 2 blocks/CU.  One barrier per K-tile.
// XOR swizzle both-sides.  Grid 16x32 = 512 blocks = one round of 512.
// ---------------------------------------------------------------------------
__global__ __launch_bounds__(256, 2)
void mfma_gemm_out(const unsigned short* __restrict__ A,
                   const unsigned short* __restrict__ W,
                   float* __restrict__ FO)
{
    constexpr int K  = 2048;
    constexpr int NT = K / 64;              // 32 K-tiles
    constexpr int BM = 128, BN = 128;
    constexpr int SLOT_US = (BM + BN) * 64; // 16384 ushorts = 32 KiB

    __shared__ unsigned short lds[2 * SLOT_US];   // 64 KiB -> 2 blocks/CU

    const int t    = threadIdx.x;
    const int w    = t >> 6, lane = t & 63;
    const int wm   = w >> 1, wn = w & 1;          // 2M x 2N
    const int m0   = blockIdx.y * BM, n0 = blockIdx.x * BN;
    const int r16  = lane & 15, q4 = lane >> 4;
    const int lxor = (r16 & 7) << 4;

    const int srow8 = lane >> 3;
    const int sgcol = (((lane & 7) ^ srow8) << 4);
    const char* Agb = (const char*)A;
    const char* Wgb = (const char*)W;

    f32x4 acc[4][4];
#pragma unroll
    for (int i = 0; i < 4; ++i)
#pragma unroll
        for (int j = 0; j < 4; ++j)
            acc[i][j] = (f32x4){0.f, 0.f, 0.f, 0.f};

// stage full K-tile: A 16 gld (ia=w*4+p), B 16 gld (ib=w*4+p); 8 per wave
#define STAGE_ALL(tt, sl) do {                                               \
    _Pragma("unroll") for (int p = 0; p < 4; ++p) {                          \
        int ia_ = w * 4 + p;                                                 \
        gld16(Agb + (size_t)(m0 + ia_ * 8 + srow8) * (K * 2) + (tt) * 128 + sgcol, \
              &lds[(sl) * SLOT_US + ia_ * 512]);                             \
    }                                                                        \
    _Pragma("unroll") for (int p = 0; p < 4; ++p) {                          \
        int ib_ = w * 4 + p;                                                 \
        gld16(Wgb + (size_t)(n0 + ib_ * 8 + srow8) * (K * 2) + (tt) * 128 + sgcol, \
              &lds[(sl) * SLOT_US + BM * 64 + ib_ * 512]);                   \
    }                                                                        \
} while (0)

#define MFMA16() do {                                                        \
    __builtin_amdgcn_s_setprio(1);                                           \
    _Pragma("unroll") for (int mi = 0; mi < 4; ++mi)                         \
    _Pragma("unroll") for (int ni = 0; ni < 4; ++ni)                         \
        acc[mi][ni] = __builtin_amdgcn_mfma_f32_16x16x32_bf16(                \
            a[mi], b[ni], acc[mi][ni], 0, 0, 0);                             \
    __builtin_amdgcn_s_setprio(0);                                           \
} while (0)

    STAGE_ALL(0, 0);
    asm volatile("s_waitcnt vmcnt(0)" ::: "memory");
    __builtin_amdgcn_s_barrier();
    asm volatile("" ::: "memory");

    for (int tt = 0; tt < NT; ++tt) {
        const int slot = tt & 1;
        const char* Ab = (const char*)&lds[slot * SLOT_US];
        const char* Bp = (const char*)&lds[slot * SLOT_US + BM * 64];
        const int c0 = (q4 * 16) ^ lxor;
        const int c1 = (64 + q4 * 16) ^ lxor;

        s16x8 a[4], b[4];

#pragma unroll
        for (int mi = 0; mi < 4; ++mi)
            a[mi] = *(const s16x8*)(Ab + (wm * 64 + mi * 16 + r16) * 128 + c0);
#pragma unroll
        for (int ni = 0; ni < 4; ++ni)
            b[ni] = *(const s16x8*)(Bp + (wn * 64 + ni * 16 + r16) * 128 + c0);
        if (tt + 1 < NT) STAGE_ALL(tt + 1, slot ^ 1);
        MFMA16();

#pragma unroll
        for (int mi = 0; mi < 4; ++mi)
            a[mi] = *(const s16x8*)(Ab + (wm * 64 + mi * 16 + r16) * 128 + c1);
#pragma unroll
        for (int ni = 0; ni < 4; ++ni)
            b[ni] = *(const s16x8*)(Bp + (wn * 64 + ni * 16 + r16) * 128 + c1);
        MFMA16();

        asm volatile("s_waitcnt vmcnt(0)" ::: "memory");
        __builtin_amdgcn_s_barrier();
        asm volatile("" ::: "memory");
    }
#undef STAGE_ALL
#undef MFMA16

#pragma unroll
    for (int mi = 0; mi < 4; ++mi)
#pragma unroll
        for (int ni = 0; ni < 4; ++ni) {
            int n = n0 + wn * 64 + ni * 16 + r16;
#pragma unroll
            for (int r = 0; r < 4; ++r) {
                int m = m0 + wm * 64 + mi * 16 + q4 * 4 + r;
                FO[(size_t)m * Dd + n] = acc[mi][ni][r];
            }
        }
}

// ---------------------------------------------------------------------------
// Flash attention (R3-proven): 32x32x16 bf16 MFMA, no-max softmax,
// double-buffered async gld_lds staging, XOR-swizzled linear LDS,
// one barrier per 64-key tile, setprio on MFMA clusters.
// LDS = 80 KiB -> 2 blocks/CU.
// ---------------------------------------------------------------------------
__global__ __launch_bounds__(256)
void flash_attn(const unsigned short* __restrict__ q,
                const unsigned short* __restrict__ k,
                const unsigned short* __restrict__ vT,
                unsigned short* __restrict__ ctx)
{
    __shared__ unsigned short Ks[2][64 * 128];   // [key][d] linear
    __shared__ unsigned short Vs[2][128 * 64];   // [d][key] linear
    __shared__ unsigned short Ps[4][32 * 64];    // per-wave [m][key]

    const int t = threadIdx.x;
    const int w = t >> 6, lane = t & 63;
    const int n32 = lane & 31, half = lane >> 5;
    const int bh = blockIdx.x >> 4;              // 16 q-tiles of 128 per (b,h)
    const int l0 = (blockIdx.x & 15) * 128;

    const unsigned short* qb = q  + ((size_t)bh * Ll + l0 + w * 32) * Hd;
    const unsigned short* kb = k  + (size_t)bh * Ll * Hd;
    const unsigned short* vb = vT + (size_t)bh * Hd * Ll;

    const int k_r = lane >> 4, k_u = lane & 15;  // K: 4 rows x 256 B per instr
    const int v_r = lane >> 3, v_u = lane & 7;   // V: 8 rows x 128 B per instr

#define STAGE(J0, bsel) do {                                                  \
    _Pragma("unroll") for (int p = 0; p < 4; ++p) {                           \
        int j_ = w * 4 + p;                                                   \
        int row_ = j_ * 4 + k_r;                                              \
        gld16(kb + (size_t)((J0) + row_) * Hd + ((k_u ^ (row_ & 7)) * 8),     \
              &Ks[bsel][j_ * 512]);                                           \
    }                                                                         \
    _Pragma("unroll") for (int p = 0; p < 4; ++p) {                           \
        int j_ = w * 4 + p;                                                   \
        int row_ = j_ * 8 + v_r;                                              \
        gld16(vb + (size_t)row_ * Ll + (J0) + ((v_u ^ (row_ & 7)) * 8),       \
              &Vs[bsel][j_ * 512]);                                           \
    }                                                                         \
} while (0)

    s16x8 qf[8];
#pragma unroll
    for (int ks = 0; ks < 8; ++ks)
        qf[ks] = *(const s16x8*)(qb + (size_t)n32 * Hd + ks * 16 + half * 8);

    f32x16 o[4];
    float lacc[16];
#pragma unroll
    for (int nt = 0; nt < 4; ++nt)
#pragma unroll
        for (int r = 0; r < 16; ++r) o[nt][r] = 0.f;
#pragma unroll
    for (int r = 0; r < 16; ++r) lacc[r] = 0.f;

    unsigned short* Pw = Ps[w];
    const int psw = (n32 & 7) << 3;              // read-side swizzle (row n32)

    STAGE(0, 0);
    __syncthreads();

    int buf = 0;
    for (int j0 = 0; j0 < Ll; j0 += 64) {
        if (j0 + 64 < Ll) STAGE(j0 + 64, buf ^ 1);   // in flight across compute

        f32x16 s0, s1;
#pragma unroll
        for (int r = 0; r < 16; ++r) { s0[r] = 0.f; s1[r] = 0.f; }
        __builtin_amdgcn_s_setprio(1);
#pragma unroll
        for (int ks = 0; ks < 8; ++ks) {
            int kc = (ks * 16 + half * 8) ^ psw;
            s16x8 b0 = *(const s16x8*)&Ks[buf][n32 * 128 + kc];
            s16x8 b1 = *(const s16x8*)&Ks[buf][(32 + n32) * 128 + kc];
            s0 = __builtin_amdgcn_mfma_f32_32x32x16_bf16(qf[ks], b0, s0, 0, 0, 0);
            s1 = __builtin_amdgcn_mfma_f32_32x32x16_bf16(qf[ks], b1, s1, 0, 0, 0);
        }
        __builtin_amdgcn_s_setprio(0);

#pragma unroll
        for (int r = 0; r < 16; ++r) {
            int mrow = (r & 3) + 8 * (r >> 2) + 4 * half;
            int sw = (mrow & 7) << 3;
            float p0 = fast_exp2(s0[r]);
            float p1 = fast_exp2(s1[r]);
            lacc[r] += p0 + p1;
            union { float f; unsigned u; } u0, u1;
            u0.f = p0; u1.f = p1;
            Pw[mrow * 64 + (n32 ^ sw)]        = (unsigned short)((u0.u + 0x8000u) >> 16);
            Pw[mrow * 64 + ((32 + n32) ^ sw)] = (unsigned short)((u1.u + 0x8000u) >> 16);
        }

        __builtin_amdgcn_s_setprio(1);
#pragma unroll
        for (int kst = 0; kst < 4; ++kst) {
            int cc = (kst * 16 + half * 8) ^ psw;
            s16x8 pf2 = *(const s16x8*)&Pw[n32 * 64 + cc];
#pragma unroll
            for (int nt = 0; nt < 4; ++nt) {
                s16x8 vf = *(const s16x8*)&Vs[buf][(nt * 32 + n32) * 64 + cc];
                o[nt] = __builtin_amdgcn_mfma_f32_32x32x16_bf16(pf2, vf, o[nt], 0, 0, 0);
            }
        }
        __builtin_amdgcn_s_setprio(0);

        __syncthreads();     // drains vmcnt(0): next tile staged; buffer swap
        buf ^= 1;
    }
#undef STAGE

    float linv[16];
#pragma unroll
    for (int r = 0; r < 16; ++r) {
        float s = lacc[r];
        s += __shfl_xor(s, 1, 64);
        s += __shfl_xor(s, 2, 64);
        s += __shfl_xor(s, 4, 64);
        s += __shfl_xor(s, 8, 64);
        s += __shfl_xor(s, 16, 64);
        linv[r] = 1.0f / s;
    }

    const int b = bh >> 4, h = bh & 15;
#pragma unroll
    for (int nt = 0; nt < 4; ++nt)
#pragma unroll
        for (int r = 0; r < 16; ++r) {
            int mrow = (r & 3) + 8 * (r >> 2) + 4 * half;
            int lq = l0 + w * 32 + mrow;
            ctx[((size_t)(b * Ll + lq)) * Dd + h * Hd + nt * 32 + n32] =
                f2bf(o[nt][r] * linv[r]);
        }
}

// ---------------------------------------------------------------------------
// Workspace (96 MB): [Xb 16M][Wq 8M][Wk 8M][Wv 8M][Wo 8M][q 16M][k 16M][vT 16M]
// Wq/Wk/Wv contiguous -> fused QKV GEMM reads them as one [6144][2048] W.
// ctx reuses the Xb slot (X dead after QKV GEMM).
// Pipeline: f2bf_all -> mfma_gemm_qkv (rope fused) -> flash_attn -> out-proj
// (rope kernel eliminated: ~13 us kernel + ~15 us launch gap).
// ---------------------------------------------------------------------------
extern "C" void kernel_launch(void* const* d_in, const int* in_sizes, int n_in,
                              void* d_out, int out_size, void* d_ws, size_t ws_size,
                              hipStream_t stream)
{
    const float* hs   = (const float*)d_in[0];
    const float* cosb = (const float*)d_in[1];
    const float* sinb = (const float*)d_in[2];
    const float* wq   = (const float*)d_in[3];
    const float* wk   = (const float*)d_in[4];
    const float* wv   = (const float*)d_in[5];
    const float* wo   = (const float*)d_in[6];
    float* out = (float*)d_out;

    char* ws = (char*)d_ws;
    unsigned short* Xb  = (unsigned short*)(ws);
    unsigned short* Wqb = (unsigned short*)(ws + (16ull << 20));
    unsigned short* Wkb = (unsigned short*)(ws + (24ull << 20));
    unsigned short* Wvb = (unsigned short*)(ws + (32ull << 20));
    unsigned short* Wob = (unsigned short*)(ws + (40ull << 20));
    unsigned short* qb  = (unsigned short*)(ws + (48ull << 20));
    unsigned short* kb  = (unsigned short*)(ws + (64ull << 20));
    unsigned short* vTb = (unsigned short*)(ws + (80ull << 20));
    unsigned short* ctx = Xb;

    // fp32 -> bf16, all tensors, one launch (24576 blocks)
    f2bf_all<<<dim3(24576), dim3(256), 0, stream>>>(
        hs, wq, wk, wv, wo, Xb, Wqb, Wkb, Wvb, Wob);

    // Fused QKV projection + RoPE: A [4096x2048] x W [6144x2048]^T
    // BM=128 x BN=128: grid 48x32 = 1536 blocks = 3 rounds of 512, 2/CU
    mfma_gemm_qkv<<<dim3(6144 / 128, M / 128), dim3(256), 0, stream>>>(
        Xb, Wqb, cosb, sinb, qb, kb, vTb);

    // Flash attention: 128 q-rows/block, 512 blocks (exactly 2/CU)
    flash_attn<<<dim3(Bb * Hh * (Ll / 128)), dim3(256), 0, stream>>>(qb, kb, vTb, ctx);

    // Output projection -> fp32 d_out
    // BM=128 x BN=128: grid 16x32 = 512 blocks = one round of 512, 2/CU
    mfma_gemm_out<<<dim3(Dd / 128, M / 128), dim3(256), 0, stream>>>(
        ctx, Wob, out);
}

// Round 14
// 370.089 us; speedup vs baseline: 1.0577x; 1.0577x over previous
//
#include <hip/hip_runtime.h>

// Problem constants
constexpr int Bb = 2;
constexpr int Ll = 2048;
constexpr int Dd = 2048;
constexpr int Hh = 16;
constexpr int Hd = 128;
constexpr int M  = Bb * Ll;   // 4096

typedef __attribute__((ext_vector_type(8)))  short s16x8;   // 8 bf16 (4 VGPRs)
typedef __attribute__((ext_vector_type(4)))  float f32x4;   // 16x16 C/D
typedef __attribute__((ext_vector_type(16))) float f32x16;  // 32x32 C/D

__device__ __forceinline__ unsigned short f2bf(float f) {
    union { float f; unsigned u; } v; v.f = f;
    unsigned r = v.u + 0x7fffu + ((v.u >> 16) & 1u);   // RNE
    return (unsigned short)(r >> 16);
}
__device__ __forceinline__ float bf2f(unsigned short b) {
    union { unsigned u; float f; } v; v.u = ((unsigned)b) << 16;
    return v.f;
}
__device__ __forceinline__ float fast_exp2(float x) {
#if __has_builtin(__builtin_amdgcn_exp2f)
    return __builtin_amdgcn_exp2f(x);
#else
    return exp2f(x);
#endif
}

// async global->LDS, 16 B per lane; lds dest = wave-uniform base + lane*16
__device__ __forceinline__ void gld16(const void* g, void* l) {
#if __has_builtin(__builtin_amdgcn_global_load_lds)
    __builtin_amdgcn_global_load_lds(
        (const __attribute__((address_space(1))) unsigned int*)g,
        (__attribute__((address_space(3))) unsigned int*)l, 16, 0, 0);
#else
    int lane = threadIdx.x & 63;
    ((int4*)l)[lane] = ((const int4*)g)[0];
#endif
}

// ---------------------------------------------------------------------------
// fp32 -> bf16 conversion, all 5 tensors in ONE launch.
// Segments (exact 1024-elem blocks): X 8192 | wq 4096 | wk 4096 | wv 4096 |
// wo 4096 = 24576 blocks total.
// wq/wk rows are PERMUTED on write: source row n = h*128+d lands at physical
// row p = h*128 + 2*(d&63) + (d>>6).  Then in the QKV GEMM output, the RoPE
// partner column d^64 sits at physical column p^1 (adjacent lane in the MFMA
// fragment) -> rope becomes a single in-register shfl_xor in the epilogue.
// cos/sin need only d&63 = (p&127)>>1 (table is concat([freqs,freqs])).
// wv/wo unpermuted.
// ---------------------------------------------------------------------------
__global__ __launch_bounds__(256)
void f2bf_all(const float* __restrict__ x,  const float* __restrict__ wq,
              const float* __restrict__ wk, const float* __restrict__ wv,
              const float* __restrict__ wo,
              unsigned short* __restrict__ Xb,  unsigned short* __restrict__ Wqb,
              unsigned short* __restrict__ Wkb, unsigned short* __restrict__ Wvb,
              unsigned short* __restrict__ Wob)
{
    int bid = blockIdx.x;
    const float* in; unsigned short* out; int off; bool perm = false;
    if      (bid <  8192) { in = x;  out = Xb;  off = bid; }
    else if (bid < 12288) { in = wq; out = Wqb; off = bid - 8192;  perm = true; }
    else if (bid < 16384) { in = wk; out = Wkb; off = bid - 12288; perm = true; }
    else if (bid < 20480) { in = wv; out = Wvb; off = bid - 16384; }
    else                  { in = wo; out = Wob; off = bid - 20480; }
    int i = (off * 256 + threadIdx.x) * 4;
    size_t j = (size_t)i;
    if (perm) {
        int n = i >> 11;          // source row (2048 elems/row)
        int c = i & 2047;         // col within row
        int p = (n & ~127) | (((n & 63) << 1) | ((n >> 6) & 1));
        j = ((size_t)p << 11) | c;
    }
    float4 v = *(const float4*)(in + i);
    ushort4 o;
    o.x = f2bf(v.x); o.y = f2bf(v.y); o.z = f2bf(v.z); o.w = f2bf(v.w);
    *(ushort4*)(out + j) = o;
}

// ---------------------------------------------------------------------------
// Fused QKV GEMM + in-register RoPE (R12 main loop bit-for-bit; only the
// q/k epilogue changes): C = A * Wall^T.  A [4096][2048] bf16,
// Wall [6144][2048] (wq;wk permuted, wv plain -- see f2bf_all).
// BM=128 x BN=192, BK=64, 256 threads = 4 waves (2M x 2N), per-wave 64x96.
// LDS: 2 slots x 40 KiB = 80 KiB -> 2 blocks/CU.  Per K-tile: ks0 frags ->
// 10 gld_lds for t+1 -> 24 MFMA -> ks1 frags -> 24 MFMA -> vmcnt(0) ->
// one barrier.  XOR swizzle both-sides.  Grid 32x32 = 1024 blocks.
// Epilogue q/k: physical col p within head has partner p^1 = lane r16^1 in
// the SAME acc register -> xp = __shfl_xor(x,1); logical d = (p&1)*64 +
// (p&127)/2; res = x*cos + sgn*xp*sin (sgn = p&1 ? + : -), q scaled by
// QS = log2(e)/sqrt(128); one bf16 rounding.  Rope kernel DELETED.
// ---------------------------------------------------------------------------
__global__ __launch_bounds__(256, 2)
void mfma_gemm_qkv(const unsigned short* __restrict__ A,
                   const unsigned short* __restrict__ Wall,
                   const float* __restrict__ cosb,
                   const float* __restrict__ sinb,
                   unsigned short* __restrict__ Oq,
                   unsigned short* __restrict__ Ok,
                   unsigned short* __restrict__ Ov)
{
    constexpr int K  = 2048;
    constexpr int NT = K / 64;              // 32 K-tiles
    constexpr int BM = 128, BN = 192;
    constexpr int SLOT_US = (BM + BN) * 64; // 20480 ushorts = 40 KiB

    __shared__ unsigned short lds[2 * SLOT_US];   // 80 KiB -> 2 blocks/CU

    const int t    = threadIdx.x;
    const int w    = t >> 6, lane = t & 63;
    const int wm   = w >> 1, wn = w & 1;          // 2M x 2N
    const int m0   = blockIdx.y * BM, n0 = blockIdx.x * BN;
    const int r16  = lane & 15, q4 = lane >> 4;
    const int lxor = (r16 & 7) << 4;              // read-side swizzle XOR

    // staging lane constants: 8 lanes per 128B row; swizzled source column
    const int srow8 = lane >> 3;
    const int sgcol = (((lane & 7) ^ srow8) << 4);
    const char* Agb = (const char*)A;
    const char* Wgb = (const char*)Wall;

    f32x4 acc[4][6];
#pragma unroll
    for (int i = 0; i < 4; ++i)
#pragma unroll
        for (int j = 0; j < 6; ++j)
            acc[i][j] = (f32x4){0.f, 0.f, 0.f, 0.f};

// stage full K-tile: A 16 gld (ia=w*4+p), B 24 gld (ib=w*6+p); 10 per wave
#define STAGE_ALL(tt, sl) do {                                               \
    _Pragma("unroll") for (int p = 0; p < 4; ++p) {                          \
        int ia_ = w * 4 + p;                                                 \
        gld16(Agb + (size_t)(m0 + ia_ * 8 + srow8) * (K * 2) + (tt) * 128 + sgcol, \
              &lds[(sl) * SLOT_US + ia_ * 512]);                             \
    }                                                                        \
    _Pragma("unroll") for (int p = 0; p < 6; ++p) {                          \
        int ib_ = w * 6 + p;                                                 \
        gld16(Wgb + (size_t)(n0 + ib_ * 8 + srow8) * (K * 2) + (tt) * 128 + sgcol, \
              &lds[(sl) * SLOT_US + BM * 64 + ib_ * 512]);                   \
    }                                                                        \
} while (0)

#define MFMA24() do {                                                        \
    __builtin_amdgcn_s_setprio(1);                                           \
    _Pragma("unroll") for (int mi = 0; mi < 4; ++mi)                         \
    _Pragma("unroll") for (int ni = 0; ni < 6; ++ni)                         \
        acc[mi][ni] = __builtin_amdgcn_mfma_f32_16x16x32_bf16(                \
            a[mi], b[ni], acc[mi][ni], 0, 0, 0);                             \
    __builtin_amdgcn_s_setprio(0);                                           \
} while (0)

    // prologue: stage tile 0 into slot 0
    STAGE_ALL(0, 0);
    asm volatile("s_waitcnt vmcnt(0)" ::: "memory");
    __builtin_amdgcn_s_barrier();
    asm volatile("" ::: "memory");

    for (int tt = 0; tt < NT; ++tt) {
        const int slot = tt & 1;
        const char* Ab = (const char*)&lds[slot * SLOT_US];
        const char* Bp = (const char*)&lds[slot * SLOT_US + BM * 64];
        const int c0 = (q4 * 16) ^ lxor;         // ksub0 byte col (swizzled)
        const int c1 = (64 + q4 * 16) ^ lxor;    // ksub1

        s16x8 a[4], b[6];

        // ks0 frags
#pragma unroll
        for (int mi = 0; mi < 4; ++mi)
            a[mi] = *(const s16x8*)(Ab + (wm * 64 + mi * 16 + r16) * 128 + c0);
#pragma unroll
        for (int ni = 0; ni < 6; ++ni)
            b[ni] = *(const s16x8*)(Bp + (wn * 96 + ni * 16 + r16) * 128 + c0);
        // issue next tile's staging early (distance ~1 tile to the wait)
        if (tt + 1 < NT) STAGE_ALL(tt + 1, slot ^ 1);
        MFMA24();

        // ks1 frags
#pragma unroll
        for (int mi = 0; mi < 4; ++mi)
            a[mi] = *(const s16x8*)(Ab + (wm * 64 + mi * 16 + r16) * 128 + c1);
#pragma unroll
        for (int ni = 0; ni < 6; ++ni)
            b[ni] = *(const s16x8*)(Bp + (wn * 96 + ni * 16 + r16) * 128 + c1);
        MFMA24();

        asm volatile("s_waitcnt vmcnt(0)" ::: "memory");  // t+1 staged
        __builtin_amdgcn_s_barrier();
        asm volatile("" ::: "memory");
    }
#undef STAGE_ALL
#undef MFMA24

    // epilogue: per frag-column routing (nb 16-aligned -> wave-uniform nsel;
    // heads 128-aligned -> each 16-col frag lies in exactly one head)
#pragma unroll
    for (int ni = 0; ni < 6; ++ni) {
        int nb   = n0 + wn * 96 + ni * 16;
        int nsel = nb >> 11;                // 0=q, 1=k, 2=v
        int nr   = nb & 2047;
        int h    = nr >> 7;
        if (nsel < 2) {
            // q/k: in-register RoPE via shfl_xor(.,1) (permuted columns)
            const float sc = (nsel == 0) ? 0.1275175f : 1.0f; // log2(e)/sqrt(128)
            unsigned short* O = nsel ? Ok : Oq;
            int p127 = (nr & 127) + r16;          // physical col within head
            int dd   = p127 >> 1;                 // logical d & 63
            int d    = ((p127 & 1) << 6) | dd;    // logical d
            float sgn = (p127 & 1) ? 1.f : -1.f;  // rotate_half sign
#pragma unroll
            for (int mi = 0; mi < 4; ++mi)
#pragma unroll
                for (int r = 0; r < 4; ++r) {
                    int m = m0 + wm * 64 + mi * 16 + q4 * 4 + r;
                    int b = m >> 11, l = m & 2047;
                    float x  = acc[mi][ni][r];
                    float xp = __shfl_xor(x, 1, 64);
                    float c  = cosb[(size_t)l * Hd + dd];
                    float s  = sinb[(size_t)l * Hd + dd];
                    float res = fmaf(x, c, sgn * xp * s) * sc;
                    O[(((size_t)b * Hh + h) * Ll + l) * Hd + d] = f2bf(res);
                }
        } else {
            // v: transposed store [b][h][d][l]; lane holds 4 consecutive l
            int d = (nr & 127) + r16;
#pragma unroll
            for (int mi = 0; mi < 4; ++mi) {
                int mb = m0 + wm * 64 + mi * 16 + q4 * 4;
                int b = mb >> 11, l = mb & 2047;
                ushort4 pk;
                pk.x = f2bf(acc[mi][ni][0]);
                pk.y = f2bf(acc[mi][ni][1]);
                pk.z = f2bf(acc[mi][ni][2]);
                pk.w = f2bf(acc[mi][ni][3]);
                *(ushort4*)&Ov[(((size_t)b * Hh + h) * Hd + d) * Ll + l] = pk;
            }
        }
    }
}

// ---------------------------------------------------------------------------
// Out-projection GEMM (R12-proven): C = A * W^T, fp32.
// BM=128 x BN=128, BK=64, 256 threads = 4 waves (2M x 2N), per-wave 64x64.
// LDS: 2 slots x 32 KiB = 64 KiB -> 2 blocks/CU.  One barrier per K-tile.
// XOR swizzle both-sides.  Grid 16x32 = 512 blocks = one round of 512.
// ---------------------------------------------------------------------------
__global__ __launch_bounds__(256, 2)
void mfma_gemm_out(const unsigned short* __restrict__ A,
                   const unsigned short* __restrict__ W,
                   float* __restrict__ FO)
{
    constexpr int K  = 2048;
    constexpr int NT = K / 64;              // 32 K-tiles
    constexpr int BM = 128, BN = 128;
    constexpr int SLOT_US = (BM + BN) * 64; // 16384 ushorts = 32 KiB

    __shared__ unsigned short lds[2 * SLOT_US];   // 64 KiB -> 2 blocks/CU

    const int t    = threadIdx.x;
    const int w    = t >> 6, lane = t & 63;
    const int wm   = w >> 1, wn = w & 1;          // 2M x 2N
    const int m0   = blockIdx.y * BM, n0 = blockIdx.x * BN;
    const int r16  = lane & 15, q4 = lane >> 4;
    const int lxor = (r16 & 7) << 4;

    const int srow8 = lane >> 3;
    const int sgcol = (((lane & 7) ^ srow8) << 4);
    const char* Agb = (const char*)A;
    const char* Wgb = (const char*)W;

    f32x4 acc[4][4];
#pragma unroll
    for (int i = 0; i < 4; ++i)
#pragma unroll
        for (int j = 0; j < 4; ++j)
            acc[i][j] = (f32x4){0.f, 0.f, 0.f, 0.f};

// stage full K-tile: A 16 gld (ia=w*4+p), B 16 gld (ib=w*4+p); 8 per wave
#define STAGE_ALL(tt, sl) do {                                               \
    _Pragma("unroll") for (int p = 0; p < 4; ++p) {                          \
        int ia_ = w * 4 + p;                                                 \
        gld16(Agb + (size_t)(m0 + ia_ * 8 + srow8) * (K * 2) + (tt) * 128 + sgcol, \
              &lds[(sl) * SLOT_US + ia_ * 512]);                             \
    }                                                                        \
    _Pragma("unroll") for (int p = 0; p < 4; ++p) {                          \
        int ib_ = w * 4 + p;                                                 \
        gld16(Wgb + (size_t)(n0 + ib_ * 8 + srow8) * (K * 2) + (tt) * 128 + sgcol, \
              &lds[(sl) * SLOT_US + BM * 64 + ib_ * 512]);                   \
    }                                                                        \
} while (0)

#define MFMA16() do {                                                        \
    __builtin_amdgcn_s_setprio(1);                                           \
    _Pragma("unroll") for (int mi = 0; mi < 4; ++mi)                         \
    _Pragma("unroll") for (int ni = 0; ni < 4; ++ni)                         \
        acc[mi][ni] = __builtin_amdgcn_mfma_f32_16x16x32_bf16(                \
            a[mi], b[ni], acc[mi][ni], 0, 0, 0);                             \
    __builtin_amdgcn_s_setprio(0);                                           \
} while (0)

    STAGE_ALL(0, 0);
    asm volatile("s_waitcnt vmcnt(0)" ::: "memory");
    __builtin_amdgcn_s_barrier();
    asm volatile("" ::: "memory");

    for (int tt = 0; tt < NT; ++tt) {
        const int slot = tt & 1;
        const char* Ab = (const char*)&lds[slot * SLOT_US];
        const char* Bp = (const char*)&lds[slot * SLOT_US + BM * 64];
        const int c0 = (q4 * 16) ^ lxor;
        const int c1 = (64 + q4 * 16) ^ lxor;

        s16x8 a[4], b[4];

#pragma unroll
        for (int mi = 0; mi < 4; ++mi)
            a[mi] = *(const s16x8*)(Ab + (wm * 64 + mi * 16 + r16) * 128 + c0);
#pragma unroll
        for (int ni = 0; ni < 4; ++ni)
            b[ni] = *(const s16x8*)(Bp + (wn * 64 + ni * 16 + r16) * 128 + c0);
        if (tt + 1 < NT) STAGE_ALL(tt + 1, slot ^ 1);
        MFMA16();

#pragma unroll
        for (int mi = 0; mi < 4; ++mi)
            a[mi] = *(const s16x8*)(Ab + (wm * 64 + mi * 16 + r16) * 128 + c1);
#pragma unroll
        for (int ni = 0; ni < 4; ++ni)
            b[ni] = *(const s16x8*)(Bp + (wn * 64 + ni * 16 + r16) * 128 + c1);
        MFMA16();

        asm volatile("s_waitcnt vmcnt(0)" ::: "memory");
        __builtin_amdgcn_s_barrier();
        asm volatile("" ::: "memory");
    }
#undef STAGE_ALL
#undef MFMA16

#pragma unroll
    for (int mi = 0; mi < 4; ++mi)
#pragma unroll
        for (int ni = 0; ni < 4; ++ni) {
            int n = n0 + wn * 64 + ni * 16 + r16;
#pragma unroll
            for (int r = 0; r < 4; ++r) {
                int m = m0 + wm * 64 + mi * 16 + q4 * 4 + r;
                FO[(size_t)m * Dd + n] = acc[mi][ni][r];
            }
        }
}

// ---------------------------------------------------------------------------
// Flash attention (R3-proven): 32x32x16 bf16 MFMA, no-max softmax,
// double-buffered async gld_lds staging, XOR-swizzled linear LDS,
// one barrier per 64-key tile, setprio on MFMA clusters.
// LDS = 80 KiB -> 2 blocks/CU.
// ---------------------------------------------------------------------------
__global__ __launch_bounds__(256)
void flash_attn(const unsigned short* __restrict__ q,
                const unsigned short* __restrict__ k,
                const unsigned short* __restrict__ vT,
                unsigned short* __restrict__ ctx)
{
    __shared__ unsigned short Ks[2][64 * 128];   // [key][d] linear
    __shared__ unsigned short Vs[2][128 * 64];   // [d][key] linear
    __shared__ unsigned short Ps[4][32 * 64];    // per-wave [m][key]

    const int t = threadIdx.x;
    const int w = t >> 6, lane = t & 63;
    const int n32 = lane & 31, half = lane >> 5;
    const int bh = blockIdx.x >> 4;              // 16 q-tiles of 128 per (b,h)
    const int l0 = (blockIdx.x & 15) * 128;

    const unsigned short* qb = q  + ((size_t)bh * Ll + l0 + w * 32) * Hd;
    const unsigned short* kb = k  + (size_t)bh * Ll * Hd;
    const unsigned short* vb = vT + (size_t)bh * Hd * Ll;

    const int k_r = lane >> 4, k_u = lane & 15;  // K: 4 rows x 256 B per instr
    const int v_r = lane >> 3, v_u = lane & 7;   // V: 8 rows x 128 B per instr

#define STAGE(J0, bsel) do {                                                  \
    _Pragma("unroll") for (int p = 0; p < 4; ++p) {                           \
        int j_ = w * 4 + p;                                                   \
        int row_ = j_ * 4 + k_r;                                              \
        gld16(kb + (size_t)((J0) + row_) * Hd + ((k_u ^ (row_ & 7)) * 8),     \
              &Ks[bsel][j_ * 512]);                                           \
    }                                                                         \
    _Pragma("unroll") for (int p = 0; p < 4; ++p) {                           \
        int j_ = w * 4 + p;                                                   \
        int row_ = j_ * 8 + v_r;                                              \
        gld16(vb + (size_t)row_ * Ll + (J0) + ((v_u ^ (row_ & 7)) * 8),       \
              &Vs[bsel][j_ * 512]);                                           \
    }                                                                         \
} while (0)

    s16x8 qf[8];
#pragma unroll
    for (int ks = 0; ks < 8; ++ks)
        qf[ks] = *(const s16x8*)(qb + (size_t)n32 * Hd + ks * 16 + half * 8);

    f32x16 o[4];
    float lacc[16];
#pragma unroll
    for (int nt = 0; nt < 4; ++nt)
#pragma unroll
        for (int r = 0; r < 16; ++r) o[nt][r] = 0.f;
#pragma unroll
    for (int r = 0; r < 16; ++r) lacc[r] = 0.f;

    unsigned short* Pw = Ps[w];
    const int psw = (n32 & 7) << 3;              // read-side swizzle (row n32)

    STAGE(0, 0);
    __syncthreads();

    int buf = 0;
    for (int j0 = 0; j0 < Ll; j0 += 64) {
        if (j0 + 64 < Ll) STAGE(j0 + 64, buf ^ 1);   // in flight across compute

        f32x16 s0, s1;
#pragma unroll
        for (int r = 0; r < 16; ++r) { s0[r] = 0.f; s1[r] = 0.f; }
        __builtin_amdgcn_s_setprio(1);
#pragma unroll
        for (int ks = 0; ks < 8; ++ks) {
            int kc = (ks * 16 + half * 8) ^ psw;
            s16x8 b0 = *(const s16x8*)&Ks[buf][n32 * 128 + kc];
            s16x8 b1 = *(const s16x8*)&Ks[buf][(32 + n32) * 128 + kc];
            s0 = __builtin_amdgcn_mfma_f32_32x32x16_bf16(qf[ks], b0, s0, 0, 0, 0);
            s1 = __builtin_amdgcn_mfma_f32_32x32x16_bf16(qf[ks], b1, s1, 0, 0, 0);
        }
        __builtin_amdgcn_s_setprio(0);

#pragma unroll
        for (int r = 0; r < 16; ++r) {
            int mrow = (r & 3) + 8 * (r >> 2) + 4 * half;
            int sw = (mrow & 7) << 3;
            float p0 = fast_exp2(s0[r]);
            float p1 = fast_exp2(s1[r]);
            lacc[r] += p0 + p1;
            union { float f; unsigned u; } u0, u1;
            u0.f = p0; u1.f = p1;
            Pw[mrow * 64 + (n32 ^ sw)]        = (unsigned short)((u0.u + 0x8000u) >> 16);
            Pw[mrow * 64 + ((32 + n32) ^ sw)] = (unsigned short)((u1.u + 0x8000u) >> 16);
        }

        __builtin_amdgcn_s_setprio(1);
#pragma unroll
        for (int kst = 0; kst < 4; ++kst) {
            int cc = (kst * 16 + half * 8) ^ psw;
            s16x8 pf2 = *(const s16x8*)&Pw[n32 * 64 + cc];
#pragma unroll
            for (int nt = 0; nt < 4; ++nt) {
                s16x8 vf = *(const s16x8*)&Vs[buf][(nt * 32 + n32) * 64 + cc];
                o[nt] = __builtin_amdgcn_mfma_f32_32x32x16_bf16(pf2, vf, o[nt], 0, 0, 0);
            }
        }
        __builtin_amdgcn_s_setprio(0);

        __syncthreads();     // drains vmcnt(0): next tile staged; buffer swap
        buf ^= 1;
    }
#undef STAGE

    float linv[16];
#pragma unroll
    for (int r = 0; r < 16; ++r) {
        float s = lacc[r];
        s += __shfl_xor(s, 1, 64);
        s += __shfl_xor(s, 2, 64);
        s += __shfl_xor(s, 4, 64);
        s += __shfl_xor(s, 8, 64);
        s += __shfl_xor(s, 16, 64);
        linv[r] = 1.0f / s;
    }

    const int b = bh >> 4, h = bh & 15;
#pragma unroll
    for (int nt = 0; nt < 4; ++nt)
#pragma unroll
        for (int r = 0; r < 16; ++r) {
            int mrow = (r & 3) + 8 * (r >> 2) + 4 * half;
            int lq = l0 + w * 32 + mrow;
            ctx[((size_t)(b * Ll + lq)) * Dd + h * Hd + nt * 32 + n32] =
                f2bf(o[nt][r] * linv[r]);
        }
}

// ---------------------------------------------------------------------------
// Workspace (96 MB): [Xb 16M][Wq 8M][Wk 8M][Wv 8M][Wo 8M][q 16M][k 16M][vT 16M]
// Wq/Wk/Wv contiguous -> fused QKV GEMM reads them as one [6144][2048] W
// (wq/wk rows permuted for in-register rope; wv plain).
// ctx reuses the Xb slot (X dead after QKV GEMM).
// Pipeline: f2bf_all -> mfma_gemm_qkv (rope fused) -> flash_attn -> out-proj.
// ---------------------------------------------------------------------------
extern "C" void kernel_launch(void* const* d_in, const int* in_sizes, int n_in,
                              void* d_out, int out_size, void* d_ws, size_t ws_size,
                              hipStream_t stream)
{
    const float* hs   = (const float*)d_in[0];
    const float* cosb = (const float*)d_in[1];
    const float* sinb = (const float*)d_in[2];
    const float* wq   = (const float*)d_in[3];
    const float* wk   = (const float*)d_in[4];
    const float* wv   = (const float*)d_in[5];
    const float* wo   = (const float*)d_in[6];
    float* out = (float*)d_out;

    char* ws = (char*)d_ws;
    unsigned short* Xb  = (unsigned short*)(ws);
    unsigned short* Wqb = (unsigned short*)(ws + (16ull << 20));
    unsigned short* Wkb = (unsigned short*)(ws + (24ull << 20));
    unsigned short* Wvb = (unsigned short*)(ws + (32ull << 20));
    unsigned short* Wob = (unsigned short*)(ws + (40ull << 20));
    unsigned short* qb  = (unsigned short*)(ws + (48ull << 20));
    unsigned short* kb  = (unsigned short*)(ws + (64ull << 20));
    unsigned short* vTb = (unsigned short*)(ws + (80ull << 20));
    unsigned short* ctx = Xb;

    // fp32 -> bf16, all tensors, one launch (wq/wk rows permuted)
    f2bf_all<<<dim3(24576), dim3(256), 0, stream>>>(
        hs, wq, wk, wv, wo, Xb, Wqb, Wkb, Wvb, Wob);

    // Fused QKV projection + in-register RoPE: A [4096x2048] x W [6144x2048]^T
    // BM=128 x BN=192: grid 32x32 = 1024 blocks, 2/CU co-resident, 2 rounds
    mfma_gemm_qkv<<<dim3(6144 / 192, M / 128), dim3(256), 0, stream>>>(
        Xb, Wqb, cosb, sinb, qb, kb, vTb);

    // Flash attention: 128 q-rows/block, 512 blocks (exactly 2/CU)
    flash_attn<<<dim3(Bb * Hh * (Ll / 128)), dim3(256), 0, stream>>>(qb, kb, vTb, ctx);

    // Output projection -> fp32 d_out
    // BM=128 x BN=128: grid 16x32 = 512 blocks = one round of 512, 2/CU
    mfma_gemm_out<<<dim3(Dd / 128, M / 128), dim3(256), 0, stream>>>(
        ctx, Wob, out);
}

// Round 15
// 361.304 us; speedup vs baseline: 1.0835x; 1.0243x over previous
//
#include <hip/hip_runtime.h>

// Problem constants
constexpr int Bb = 2;
constexpr int Ll = 2048;
constexpr int Dd = 2048;
constexpr int Hh = 16;
constexpr int Hd = 128;
constexpr int M  = Bb * Ll;   // 4096

typedef __attribute__((ext_vector_type(8)))  short s16x8;   // 8 bf16 (4 VGPRs)
typedef __attribute__((ext_vector_type(4)))  float f32x4;   // 16x16 C/D
typedef __attribute__((ext_vector_type(16))) float f32x16;  // 32x32 C/D

__device__ __forceinline__ unsigned short f2bf(float f) {
    union { float f; unsigned u; } v; v.f = f;
    unsigned r = v.u + 0x7fffu + ((v.u >> 16) & 1u);   // RNE
    return (unsigned short)(r >> 16);
}
__device__ __forceinline__ float bf2f(unsigned short b) {
    union { unsigned u; float f; } v; v.u = ((unsigned)b) << 16;
    return v.f;
}
__device__ __forceinline__ float fast_exp2(float x) {
#if __has_builtin(__builtin_amdgcn_exp2f)
    return __builtin_amdgcn_exp2f(x);
#else
    return exp2f(x);
#endif
}

// async global->LDS, 16 B per lane; lds dest = wave-uniform base + lane*16
__device__ __forceinline__ void gld16(const void* g, void* l) {
#if __has_builtin(__builtin_amdgcn_global_load_lds)
    __builtin_amdgcn_global_load_lds(
        (const __attribute__((address_space(1))) unsigned int*)g,
        (__attribute__((address_space(3))) unsigned int*)l, 16, 0, 0);
#else
    int lane = threadIdx.x & 63;
    ((int4*)l)[lane] = ((const int4*)g)[0];
#endif
}

// ---------------------------------------------------------------------------
// fp32 -> bf16 conversion, all 5 tensors in ONE launch.
// Segments (exact 1024-elem blocks): X 8192 | wq 4096 | wk 4096 | wv 4096 |
// wo 4096 = 24576 blocks total.
// wq/wk rows are PERMUTED on write: source row n = h*128+d lands at physical
// row p = h*128 + 2*(d&63) + (d>>6).  Then in the QKV GEMM output, the RoPE
// partner column d^64 sits at physical column p^1 (adjacent lane in the MFMA
// fragment) -> rope becomes a single in-register shfl_xor in the epilogue.
// q/k stay in PERMUTED column layout all the way through flash_attn: QK^T is
// invariant under identical column permutations of q and k, and v/PV are
// untouched -- so no un-permutation anywhere (keeps stores coalesced).
// cos/sin need only d&63 = (p&127)>>1 (table is concat([freqs,freqs])).
// wv/wo unpermuted.
// ---------------------------------------------------------------------------
__global__ __launch_bounds__(256)
void f2bf_all(const float* __restrict__ x,  const float* __restrict__ wq,
              const float* __restrict__ wk, const float* __restrict__ wv,
              const float* __restrict__ wo,
              unsigned short* __restrict__ Xb,  unsigned short* __restrict__ Wqb,
              unsigned short* __restrict__ Wkb, unsigned short* __restrict__ Wvb,
              unsigned short* __restrict__ Wob)
{
    int bid = blockIdx.x;
    const float* in; unsigned short* out; int off; bool perm = false;
    if      (bid <  8192) { in = x;  out = Xb;  off = bid; }
    else if (bid < 12288) { in = wq; out = Wqb; off = bid - 8192;  perm = true; }
    else if (bid < 16384) { in = wk; out = Wkb; off = bid - 12288; perm = true; }
    else if (bid < 20480) { in = wv; out = Wvb; off = bid - 16384; }
    else                  { in = wo; out = Wob; off = bid - 20480; }
    int i = (off * 256 + threadIdx.x) * 4;
    size_t j = (size_t)i;
    if (perm) {
        int n = i >> 11;          // source row (2048 elems/row)
        int c = i & 2047;         // col within row
        int p = (n & ~127) | (((n & 63) << 1) | ((n >> 6) & 1));
        j = ((size_t)p << 11) | c;
    }
    float4 v = *(const float4*)(in + i);
    ushort4 o;
    o.x = f2bf(v.x); o.y = f2bf(v.y); o.z = f2bf(v.z); o.w = f2bf(v.w);
    *(ushort4*)(out + j) = o;
}

// ---------------------------------------------------------------------------
// Fused QKV GEMM + in-register RoPE: C = A * Wall^T.  A [4096][2048] bf16,
// Wall [6144][2048] (wq;wk permuted, wv plain -- see f2bf_all).
// BM=128 x BN=192, BK=64, 256 threads = 4 waves (2M x 2N), per-wave 64x96.
// LDS: 2 slots x 40 KiB = 80 KiB -> 2 blocks/CU.  Per K-tile: ks0 frags ->
// 10 gld_lds for t+1 -> 24 MFMA -> ks1 frags -> 24 MFMA -> vmcnt(0) ->
// one barrier.  XOR swizzle both-sides.  Grid 32x32 = 1024 blocks.
// Epilogue q/k: partner p^1 = lane r16^1 in the SAME acc register ->
// xp = __shfl_xor(x,1); res = x*cos + sgn*xp*sin (sgn = p&1 ? + : -),
// q scaled by QS = log2(e)/sqrt(128); one bf16 rounding; store at the
// PHYSICAL column p (permuted layout, coalesced 32B runs -- R14's
// un-permuted store scattered and cost +33 MB WRITE_SIZE).  flash_attn
// consumes the permuted q/k directly (QK^T permutation-invariant).
// ---------------------------------------------------------------------------
__global__ __launch_bounds__(256, 2)
void mfma_gemm_qkv(const unsigned short* __restrict__ A,
                   const unsigned short* __restrict__ Wall,
                   const float* __restrict__ cosb,
                   const float* __restrict__ sinb,
                   unsigned short* __restrict__ Oq,
                   unsigned short* __restrict__ Ok,
                   unsigned short* __restrict__ Ov)
{
    constexpr int K  = 2048;
    constexpr int NT = K / 64;              // 32 K-tiles
    constexpr int BM = 128, BN = 192;
    constexpr int SLOT_US = (BM + BN) * 64; // 20480 ushorts = 40 KiB

    __shared__ unsigned short lds[2 * SLOT_US];   // 80 KiB -> 2 blocks/CU

    const int t    = threadIdx.x;
    const int w    = t >> 6, lane = t & 63;
    const int wm   = w >> 1, wn = w & 1;          // 2M x 2N
    const int m0   = blockIdx.y * BM, n0 = blockIdx.x * BN;
    const int r16  = lane & 15, q4 = lane >> 4;
    const int lxor = (r16 & 7) << 4;              // read-side swizzle XOR

    // staging lane constants: 8 lanes per 128B row; swizzled source column
    const int srow8 = lane >> 3;
    const int sgcol = (((lane & 7) ^ srow8) << 4);
    const char* Agb = (const char*)A;
    const char* Wgb = (const char*)Wall;

    f32x4 acc[4][6];
#pragma unroll
    for (int i = 0; i < 4; ++i)
#pragma unroll
        for (int j = 0; j < 6; ++j)
            acc[i][j] = (f32x4){0.f, 0.f, 0.f, 0.f};

// stage full K-tile: A 16 gld (ia=w*4+p), B 24 gld (ib=w*6+p); 10 per wave
#define STAGE_ALL(tt, sl) do {                                               \
    _Pragma("unroll") for (int p = 0; p < 4; ++p) {                          \
        int ia_ = w * 4 + p;                                                 \
        gld16(Agb + (size_t)(m0 + ia_ * 8 + srow8) * (K * 2) + (tt) * 128 + sgcol, \
              &lds[(sl) * SLOT_US + ia_ * 512]);                             \
    }                                                                        \
    _Pragma("unroll") for (int p = 0; p < 6; ++p) {                          \
        int ib_ = w * 6 + p;                                                 \
        gld16(Wgb + (size_t)(n0 + ib_ * 8 + srow8) * (K * 2) + (tt) * 128 + sgcol, \
              &lds[(sl) * SLOT_US + BM * 64 + ib_ * 512]);                   \
    }                                                                        \
} while (0)

#define MFMA24() do {                                                        \
    __builtin_amdgcn_s_setprio(1);                                           \
    _Pragma("unroll") for (int mi = 0; mi < 4; ++mi)                         \
    _Pragma("unroll") for (int ni = 0; ni < 6; ++ni)                         \
        acc[mi][ni] = __builtin_amdgcn_mfma_f32_16x16x32_bf16(                \
            a[mi], b[ni], acc[mi][ni], 0, 0, 0);                             \
    __builtin_amdgcn_s_setprio(0);                                           \
} while (0)

    // prologue: stage tile 0 into slot 0
    STAGE_ALL(0, 0);
    asm volatile("s_waitcnt vmcnt(0)" ::: "memory");
    __builtin_amdgcn_s_barrier();
    asm volatile("" ::: "memory");

    for (int tt = 0; tt < NT; ++tt) {
        const int slot = tt & 1;
        const char* Ab = (const char*)&lds[slot * SLOT_US];
        const char* Bp = (const char*)&lds[slot * SLOT_US + BM * 64];
        const int c0 = (q4 * 16) ^ lxor;         // ksub0 byte col (swizzled)
        const int c1 = (64 + q4 * 16) ^ lxor;    // ksub1

        s16x8 a[4], b[6];

        // ks0 frags
#pragma unroll
        for (int mi = 0; mi < 4; ++mi)
            a[mi] = *(const s16x8*)(Ab + (wm * 64 + mi * 16 + r16) * 128 + c0);
#pragma unroll
        for (int ni = 0; ni < 6; ++ni)
            b[ni] = *(const s16x8*)(Bp + (wn * 96 + ni * 16 + r16) * 128 + c0);
        // issue next tile's staging early (distance ~1 tile to the wait)
        if (tt + 1 < NT) STAGE_ALL(tt + 1, slot ^ 1);
        MFMA24();

        // ks1 frags
#pragma unroll
        for (int mi = 0; mi < 4; ++mi)
            a[mi] = *(const s16x8*)(Ab + (wm * 64 + mi * 16 + r16) * 128 + c1);
#pragma unroll
        for (int ni = 0; ni < 6; ++ni)
            b[ni] = *(const s16x8*)(Bp + (wn * 96 + ni * 16 + r16) * 128 + c1);
        MFMA24();

        asm volatile("s_waitcnt vmcnt(0)" ::: "memory");  // t+1 staged
        __builtin_amdgcn_s_barrier();
        asm volatile("" ::: "memory");
    }
#undef STAGE_ALL
#undef MFMA24

    // epilogue: per frag-column routing (nb 16-aligned -> wave-uniform nsel;
    // heads 128-aligned -> each 16-col frag lies in exactly one head)
#pragma unroll
    for (int ni = 0; ni < 6; ++ni) {
        int nb   = n0 + wn * 96 + ni * 16;
        int nsel = nb >> 11;                // 0=q, 1=k, 2=v
        int nr   = nb & 2047;
        int h    = nr >> 7;
        if (nsel < 2) {
            // q/k: in-register RoPE via shfl_xor(.,1); store PERMUTED col p
            const float sc = (nsel == 0) ? 0.1275175f : 1.0f; // log2(e)/sqrt(128)
            unsigned short* O = nsel ? Ok : Oq;
            int p127 = (nr & 127) + r16;          // physical col within head
            int dd   = p127 >> 1;                 // logical d & 63
            float sgn = (p127 & 1) ? 1.f : -1.f;  // rotate_half sign
#pragma unroll
            for (int mi = 0; mi < 4; ++mi)
#pragma unroll
                for (int r = 0; r < 4; ++r) {
                    int m = m0 + wm * 64 + mi * 16 + q4 * 4 + r;
                    int b = m >> 11, l = m & 2047;
                    float x  = acc[mi][ni][r];
                    float xp = __shfl_xor(x, 1, 64);
                    float c  = cosb[(size_t)l * Hd + dd];
                    float s  = sinb[(size_t)l * Hd + dd];
                    float res = fmaf(x, c, sgn * xp * s) * sc;
                    O[(((size_t)b * Hh + h) * Ll + l) * Hd + p127] = f2bf(res);
                }
        } else {
            // v: transposed store [b][h][d][l]; lane holds 4 consecutive l
            int d = (nr & 127) + r16;
#pragma unroll
            for (int mi = 0; mi < 4; ++mi) {
                int mb = m0 + wm * 64 + mi * 16 + q4 * 4;
                int b = mb >> 11, l = mb & 2047;
                ushort4 pk;
                pk.x = f2bf(acc[mi][ni][0]);
                pk.y = f2bf(acc[mi][ni][1]);
                pk.z = f2bf(acc[mi][ni][2]);
                pk.w = f2bf(acc[mi][ni][3]);
                *(ushort4*)&Ov[(((size_t)b * Hh + h) * Hd + d) * Ll + l] = pk;
            }
        }
    }
}

// ---------------------------------------------------------------------------
// Out-projection GEMM (R12-proven): C = A * W^T, fp32.
// BM=128 x BN=128, BK=64, 256 threads = 4 waves (2M x 2N), per-wave 64x64.
// LDS: 2 slots x 32 KiB = 64 KiB -> 2 blocks/CU.  One barrier per K-tile.
// XOR swizzle both-sides.  Grid 16x32 = 512 blocks = one round of 512.
// ---------------------------------------------------------------------------
__global__ __launch_bounds__(256, 2)
void mfma_gemm_out(const unsigned short* __restrict__ A,
                   const unsigned short* __restrict__ W,
                   float* __restrict__ FO)
{
    constexpr int K  = 2048;
    constexpr int NT = K / 64;              // 32 K-tiles
    constexpr int BM = 128, BN = 128;
    constexpr int SLOT_US = (BM + BN) * 64; // 16384 ushorts = 32 KiB

    __shared__ unsigned short lds[2 * SLOT_US];   // 64 KiB -> 2 blocks/CU

    const int t    = threadIdx.x;
    const int w    = t >> 6, lane = t & 63;
    const int wm   = w >> 1, wn = w & 1;          // 2M x 2N
    const int m0   = blockIdx.y * BM, n0 = blockIdx.x * BN;
    const int r16  = lane & 15, q4 = lane >> 4;
    const int lxor = (r16 & 7) << 4;

    const int srow8 = lane >> 3;
    const int sgcol = (((lane & 7) ^ srow8) << 4);
    const char* Agb = (const char*)A;
    const char* Wgb = (const char*)W;

    f32x4 acc[4][4];
#pragma unroll
    for (int i = 0; i < 4; ++i)
#pragma unroll
        for (int j = 0; j < 4; ++j)
            acc[i][j] = (f32x4){0.f, 0.f, 0.f, 0.f};

// stage full K-tile: A 16 gld (ia=w*4+p), B 16 gld (ib=w*4+p); 8 per wave
#define STAGE_ALL(tt, sl) do {                                               \
    _Pragma("unroll") for (int p = 0; p < 4; ++p) {                          \
        int ia_ = w * 4 + p;                                                 \
        gld16(Agb + (size_t)(m0 + ia_ * 8 + srow8) * (K * 2) + (tt) * 128 + sgcol, \
              &lds[(sl) * SLOT_US + ia_ * 512]);                             \
    }                                                                        \
    _Pragma("unroll") for (int p = 0; p < 4; ++p) {                          \
        int ib_ = w * 4 + p;                                                 \
        gld16(Wgb + (size_t)(n0 + ib_ * 8 + srow8) * (K * 2) + (tt) * 128 + sgcol, \
              &lds[(sl) * SLOT_US + BM * 64 + ib_ * 512]);                   \
    }                                                                        \
} while (0)

#define MFMA16() do {                                                        \
    __builtin_amdgcn_s_setprio(1);                                           \
    _Pragma("unroll") for (int mi = 0; mi < 4; ++mi)                         \
    _Pragma("unroll") for (int ni = 0; ni < 4; ++ni)                         \
        acc[mi][ni] = __builtin_amdgcn_mfma_f32_16x16x32_bf16(                \
            a[mi], b[ni], acc[mi][ni], 0, 0, 0);                             \
    __builtin_amdgcn_s_setprio(0);                                           \
} while (0)

    STAGE_ALL(0, 0);
    asm volatile("s_waitcnt vmcnt(0)" ::: "memory");
    __builtin_amdgcn_s_barrier();
    asm volatile("" ::: "memory");

    for (int tt = 0; tt < NT; ++tt) {
        const int slot = tt & 1;
        const char* Ab = (const char*)&lds[slot * SLOT_US];
        const char* Bp = (const char*)&lds[slot * SLOT_US + BM * 64];
        const int c0 = (q4 * 16) ^ lxor;
        const int c1 = (64 + q4 * 16) ^ lxor;

        s16x8 a[4], b[4];

#pragma unroll
        for (int mi = 0; mi < 4; ++mi)
            a[mi] = *(const s16x8*)(Ab + (wm * 64 + mi * 16 + r16) * 128 + c0);
#pragma unroll
        for (int ni = 0; ni < 4; ++ni)
            b[ni] = *(const s16x8*)(Bp + (wn * 64 + ni * 16 + r16) * 128 + c0);
        if (tt + 1 < NT) STAGE_ALL(tt + 1, slot ^ 1);
        MFMA16();

#pragma unroll
        for (int mi = 0; mi < 4; ++mi)
            a[mi] = *(const s16x8*)(Ab + (wm * 64 + mi * 16 + r16) * 128 + c1);
#pragma unroll
        for (int ni = 0; ni < 4; ++ni)
            b[ni] = *(const s16x8*)(Bp + (wn * 64 + ni * 16 + r16) * 128 + c1);
        MFMA16();

        asm volatile("s_waitcnt vmcnt(0)" ::: "memory");
        __builtin_amdgcn_s_barrier();
        asm volatile("" ::: "memory");
    }
#undef STAGE_ALL
#undef MFMA16

#pragma unroll
    for (int mi = 0; mi < 4; ++mi)
#pragma unroll
        for (int ni = 0; ni < 4; ++ni) {
            int n = n0 + wn * 64 + ni * 16 + r16;
#pragma unroll
            for (int r = 0; r < 4; ++r) {
                int m = m0 + wm * 64 + mi * 16 + q4 * 4 + r;
                FO[(size_t)m * Dd + n] = acc[mi][ni][r];
            }
        }
}

// ---------------------------------------------------------------------------
// Flash attention (R3-proven): 32x32x16 bf16 MFMA, no-max softmax,
// double-buffered async gld_lds staging, XOR-swizzled linear LDS,
// one barrier per 64-key tile, setprio on MFMA clusters.
// q/k arrive in permuted column layout (QK^T invariant); v plain.
// LDS = 80 KiB -> 2 blocks/CU.
// ---------------------------------------------------------------------------
__global__ __launch_bounds__(256)
void flash_attn(const unsigned short* __restrict__ q,
                const unsigned short* __restrict__ k,
                const unsigned short* __restrict__ vT,
                unsigned short* __restrict__ ctx)
{
    __shared__ unsigned short Ks[2][64 * 128];   // [key][d] linear
    __shared__ unsigned short Vs[2][128 * 64];   // [d][key] linear
    __shared__ unsigned short Ps[4][32 * 64];    // per-wave [m][key]

    const int t = threadIdx.x;
    const int w = t >> 6, lane = t & 63;
    const int n32 = lane & 31, half = lane >> 5;
    const int bh = blockIdx.x >> 4;              // 16 q-tiles of 128 per (b,h)
    const int l0 = (blockIdx.x & 15) * 128;

    const unsigned short* qb = q  + ((size_t)bh * Ll + l0 + w * 32) * Hd;
    const unsigned short* kb = k  + (size_t)bh * Ll * Hd;
    const unsigned short* vb = vT + (size_t)bh * Hd * Ll;

    const int k_r = lane >> 4, k_u = lane & 15;  // K: 4 rows x 256 B per instr
    const int v_r = lane >> 3, v_u = lane & 7;   // V: 8 rows x 128 B per instr

#define STAGE(J0, bsel) do {                                                  \
    _Pragma("unroll") for (int p = 0; p < 4; ++p) {                           \
        int j_ = w * 4 + p;                                                   \
        int row_ = j_ * 4 + k_r;                                              \
        gld16(kb + (size_t)((J0) + row_) * Hd + ((k_u ^ (row_ & 7)) * 8),     \
              &Ks[bsel][j_ * 512]);                                           \
    }                                                                         \
    _Pragma("unroll") for (int p = 0; p < 4; ++p) {                           \
        int j_ = w * 4 + p;                                                   \
        int row_ = j_ * 8 + v_r;                                              \
        gld16(vb + (size_t)row_ * Ll + (J0) + ((v_u ^ (row_ & 7)) * 8),       \
              &Vs[bsel][j_ * 512]);                                           \
    }                                                                         \
} while (0)

    s16x8 qf[8];
#pragma unroll
    for (int ks = 0; ks < 8; ++ks)
        qf[ks] = *(const s16x8*)(qb + (size_t)n32 * Hd + ks * 16 + half * 8);

    f32x16 o[4];
    float lacc[16];
#pragma unroll
    for (int nt = 0; nt < 4; ++nt)
#pragma unroll
        for (int r = 0; r < 16; ++r) o[nt][r] = 0.f;
#pragma unroll
    for (int r = 0; r < 16; ++r) lacc[r] = 0.f;

    unsigned short* Pw = Ps[w];
    const int psw = (n32 & 7) << 3;              // read-side swizzle (row n32)

    STAGE(0, 0);
    __syncthreads();

    int buf = 0;
    for (int j0 = 0; j0 < Ll; j0 += 64) {
        if (j0 + 64 < Ll) STAGE(j0 + 64, buf ^ 1);   // in flight across compute

        f32x16 s0, s1;
#pragma unroll
        for (int r = 0; r < 16; ++r) { s0[r] = 0.f; s1[r] = 0.f; }
        __builtin_amdgcn_s_setprio(1);
#pragma unroll
        for (int ks = 0; ks < 8; ++ks) {
            int kc = (ks * 16 + half * 8) ^ psw;
            s16x8 b0 = *(const s16x8*)&Ks[buf][n32 * 128 + kc];
            s16x8 b1 = *(const s16x8*)&Ks[buf][(32 + n32) * 128 + kc];
            s0 = __builtin_amdgcn_mfma_f32_32x32x16_bf16(qf[ks], b0, s0, 0, 0, 0);
            s1 = __builtin_amdgcn_mfma_f32_32x32x16_bf16(qf[ks], b1, s1, 0, 0, 0);
        }
        __builtin_amdgcn_s_setprio(0);

#pragma unroll
        for (int r = 0; r < 16; ++r) {
            int mrow = (r & 3) + 8 * (r >> 2) + 4 * half;
            int sw = (mrow & 7) << 3;
            float p0 = fast_exp2(s0[r]);
            float p1 = fast_exp2(s1[r]);
            lacc[r] += p0 + p1;
            union { float f; unsigned u; } u0, u1;
            u0.f = p0; u1.f = p1;
            Pw[mrow * 64 + (n32 ^ sw)]        = (unsigned short)((u0.u + 0x8000u) >> 16);
            Pw[mrow * 64 + ((32 + n32) ^ sw)] = (unsigned short)((u1.u + 0x8000u) >> 16);
        }

        __builtin_amdgcn_s_setprio(1);
#pragma unroll
        for (int kst = 0; kst < 4; ++kst) {
            int cc = (kst * 16 + half * 8) ^ psw;
            s16x8 pf2 = *(const s16x8*)&Pw[n32 * 64 + cc];
#pragma unroll
            for (int nt = 0; nt < 4; ++nt) {
                s16x8 vf = *(const s16x8*)&Vs[buf][(nt * 32 + n32) * 64 + cc];
                o[nt] = __builtin_amdgcn_mfma_f32_32x32x16_bf16(pf2, vf, o[nt], 0, 0, 0);
            }
        }
        __builtin_amdgcn_s_setprio(0);

        __syncthreads();     // drains vmcnt(0): next tile staged; buffer swap
        buf ^= 1;
    }
#undef STAGE

    float linv[16];
#pragma unroll
    for (int r = 0; r < 16; ++r) {
        float s = lacc[r];
        s += __shfl_xor(s, 1, 64);
        s += __shfl_xor(s, 2, 64);
        s += __shfl_xor(s, 4, 64);
        s += __shfl_xor(s, 8, 64);
        s += __shfl_xor(s, 16, 64);
        linv[r] = 1.0f / s;
    }

    const int b = bh >> 4, h = bh & 15;
#pragma unroll
    for (int nt = 0; nt < 4; ++nt)
#pragma unroll
        for (int r = 0; r < 16; ++r) {
            int mrow = (r & 3) + 8 * (r >> 2) + 4 * half;
            int lq = l0 + w * 32 + mrow;
            ctx[((size_t)(b * Ll + lq)) * Dd + h * Hd + nt * 32 + n32] =
                f2bf(o[nt][r] * linv[r]);
        }
}

// ---------------------------------------------------------------------------
// Workspace (96 MB): [Xb 16M][Wq 8M][Wk 8M][Wv 8M][Wo 8M][q 16M][k 16M][vT 16M]
// Wq/Wk/Wv contiguous -> fused QKV GEMM reads them as one [6144][2048] W
// (wq/wk rows permuted for in-register rope; wv plain).
// ctx reuses the Xb slot (X dead after QKV GEMM).
// Pipeline: f2bf_all -> mfma_gemm_qkv (rope fused) -> flash_attn -> out-proj.
// ---------------------------------------------------------------------------
extern "C" void kernel_launch(void* const* d_in, const int* in_sizes, int n_in,
                              void* d_out, int out_size, void* d_ws, size_t ws_size,
                              hipStream_t stream)
{
    const float* hs   = (const float*)d_in[0];
    const float* cosb = (const float*)d_in[1];
    const float* sinb = (const float*)d_in[2];
    const float* wq   = (const float*)d_in[3];
    const float* wk   = (const float*)d_in[4];
    const float* wv   = (const float*)d_in[5];
    const float* wo   = (const float*)d_in[6];
    float* out = (float*)d_out;

    char* ws = (char*)d_ws;
    unsigned short* Xb  = (unsigned short*)(ws);
    unsigned short* Wqb = (unsigned short*)(ws + (16ull << 20));
    unsigned short* Wkb = (unsigned short*)(ws + (24ull << 20));
    unsigned short* Wvb = (unsigned short*)(ws + (32ull << 20));
    unsigned short* Wob = (unsigned short*)(ws + (40ull << 20));
    unsigned short* qb  = (unsigned short*)(ws + (48ull << 20));
    unsigned short* kb  = (unsigned short*)(ws + (64ull << 20));
    unsigned short* vTb = (unsigned short*)(ws + (80ull << 20));
    unsigned short* ctx = Xb;

    // fp32 -> bf16, all tensors, one launch (wq/wk rows permuted)
    f2bf_all<<<dim3(24576), dim3(256), 0, stream>>>(
        hs, wq, wk, wv, wo, Xb, Wqb, Wkb, Wvb, Wob);

    // Fused QKV projection + in-register RoPE: A [4096x2048] x W [6144x2048]^T
    // BM=128 x BN=192: grid 32x32 = 1024 blocks, 2/CU co-resident, 2 rounds
    mfma_gemm_qkv<<<dim3(6144 / 192, M / 128), dim3(256), 0, stream>>>(
        Xb, Wqb, cosb, sinb, qb, kb, vTb);

    // Flash attention: 128 q-rows/block, 512 blocks (exactly 2/CU)
    flash_attn<<<dim3(Bb * Hh * (Ll / 128)), dim3(256), 0, stream>>>(qb, kb, vTb, ctx);

    // Output projection -> fp32 d_out
    // BM=128 x BN=128: grid 16x32 = 512 blocks = one round of 512, 2/CU
    mfma_gemm_out<<<dim3(Dd / 128, M / 128), dim3(256), 0, stream>>>(
        ctx, Wob, out);
}